// Round 4
// baseline (187.303 us; speedup 1.0000x reference)
//
#include <hip/hip_runtime.h>
#include <hip/hip_cooperative_groups.h>

namespace cg = cooperative_groups;

// Bottom-up HTMM on a complete 4-ary tree, depth 7 (t_size=21845), fused into
// ONE cooperative kernel. children(u)=4u+1..4u+4, pos(u)=(u-1)&3.
// prior cancels everywhere (only numbeta = prior*beta_il is used).
// 256 blocks = 256 depth-3 subtrees (85 nodes each, state in LDS);
// top 85 nodes (levels 0..3) handled g-split by blocks 0..15 via global mem.
// Local subtree numbering is itself a complete tree: children(v)=4v+1..4v+4,
// root v=0 <-> global 85+b, leaves v=21..84 <-> 5461+64b+k.

#define G 16
#define C 8
#define GC 128
#define TSIZE 21845
#define SL 5461

struct P {
  const int* t;
  const float* a; const float* b; const float* pi; const float* sp;
  float* a_sp; float* log_a; float* sm_bT; float* log_bT;
  float* sm_piT; float* log_piT; float* log_sp;
  float* betaG; float* numG; float* epsG; float* out;
};

__device__ __forceinline__ float grp8_sum(float v) {
  v += __shfl_xor(v, 1);
  v += __shfl_xor(v, 2);
  v += __shfl_xor(v, 4);
  return v;
}

// ---- LDS subtree bodies ----
__device__ __forceinline__ void up_lds(int v, int lab, int gi, int g8,
    const float* asp, const float* __restrict__ sm_bT,
    float* sBeta, float* sNum) {
  int ch0 = 4*v + 1;
  float ub = 0.f;
  #pragma unroll
  for (int l = 0; l < 4; ++l) {
    const float4* bp = (const float4*)(sBeta + (ch0 + l)*GC + g8);
    float4 b0 = bp[0], b1 = bp[1];
    ub += asp[l]*b0.x + asp[4+l]*b0.y + asp[8+l]*b0.z + asp[12+l]*b0.w
        + asp[16+l]*b1.x + asp[20+l]*b1.y + asp[24+l]*b1.z + asp[28+l]*b1.w;
  }
  float tmp = sm_bT[lab*GC + gi] * ub;
  float s = grp8_sum(tmp);
  sBeta[v*GC + gi] = tmp / s;
  sNum[v*GC + gi]  = ub;
}

// eps of node v lives in sBeta[v] on entry (passed as e); children's beta
// slots are overwritten with children's eps (safe within-wave: each l's loads
// precede its store; stores touch only disjoint child slots).
__device__ __forceinline__ double down_lds(int v, int lab, float e, int gi, int g8,
    const float* asp, const float* aal, const float* lsp,
    const float* __restrict__ log_bT, float* sBeta, const float* sNum) {
  float pe = e / sNum[v*GC + gi];
  int ch0 = 4*v + 1;
  float local = 0.f;
  #pragma unroll
  for (int l = 0; l < 4; ++l) {
    float4* bp = (float4*)(sBeta + (ch0 + l)*GC + g8);
    float4 b0 = bp[0], b1 = bp[1];
    float S = asp[l]*b0.x + asp[4+l]*b0.y + asp[8+l]*b0.z + asp[12+l]*b0.w
            + asp[16+l]*b1.x + asp[20+l]*b1.y + asp[24+l]*b1.z + asp[28+l]*b1.w;
    float A = aal[l]*b0.x + aal[4+l]*b0.y + aal[8+l]*b0.z + aal[12+l]*b0.w
            + aal[16+l]*b1.x + aal[20+l]*b1.y + aal[24+l]*b1.z + aal[28+l]*b1.w;
    float ce = pe * S;
    sBeta[(ch0 + l)*GC + gi] = ce;          // beta slot -> eps
    local += pe*A + ce*lsp[l];
  }
  return (double)local + (double)(e * log_bT[lab*GC + gi]);
}

// ---- global top bodies (nodes 0..340) ----
__device__ __forceinline__ void up_g(int u, int lab, int gi, int g8,
    const float* asp, const float* __restrict__ sm_bT,
    float* __restrict__ betaG, float* __restrict__ numG) {
  int ch0 = 4*u + 1;
  float ub = 0.f;
  #pragma unroll
  for (int l = 0; l < 4; ++l) {
    const float4* bp = (const float4*)(betaG + (size_t)(ch0 + l)*GC + g8);
    float4 b0 = bp[0], b1 = bp[1];
    ub += asp[l]*b0.x + asp[4+l]*b0.y + asp[8+l]*b0.z + asp[12+l]*b0.w
        + asp[16+l]*b1.x + asp[20+l]*b1.y + asp[24+l]*b1.z + asp[28+l]*b1.w;
  }
  float tmp = sm_bT[lab*GC + gi] * ub;
  float s = grp8_sum(tmp);
  betaG[(size_t)u*GC + gi] = tmp / s;
  numG[(size_t)u*GC + gi]  = ub;
}

__device__ __forceinline__ double down_g(int u, int lab, int gi, int g8,
    const float* asp, const float* aal, const float* lsp,
    const float* __restrict__ log_bT, const float* __restrict__ numG,
    const float* __restrict__ betaG, float* __restrict__ epsG) {
  float e  = epsG[(size_t)u*GC + gi];
  float pe = e / numG[(size_t)u*GC + gi];
  int ch0 = 4*u + 1;
  float local = 0.f;
  #pragma unroll
  for (int l = 0; l < 4; ++l) {
    const float4* bp = (const float4*)(betaG + (size_t)(ch0 + l)*GC + g8);
    float4 b0 = bp[0], b1 = bp[1];
    float S = asp[l]*b0.x + asp[4+l]*b0.y + asp[8+l]*b0.z + asp[12+l]*b0.w
            + asp[16+l]*b1.x + asp[20+l]*b1.y + asp[24+l]*b1.z + asp[28+l]*b1.w;
    float A = aal[l]*b0.x + aal[4+l]*b0.y + aal[8+l]*b0.z + aal[12+l]*b0.w
            + aal[16+l]*b1.x + aal[20+l]*b1.y + aal[24+l]*b1.z + aal[28+l]*b1.w;
    float ce = pe * S;
    epsG[(size_t)(ch0 + l)*GC + gi] = ce;
    local += pe*A + ce*lsp[l];
  }
  return (double)local + (double)(e * log_bT[lab*GC + gi]);
}

__global__ __launch_bounds__(512, 1) void fused_kernel(P p) {
  __shared__ float  sBeta[85*GC];   // 43.5 KB; down pass overwrites with eps
  __shared__ float  sNum[21*GC];    // 10.75 KB (internal nodes)
  __shared__ double sd[64];
  __shared__ float  red[2][4];
  cg::grid_group grid = cg::this_grid();
  const int blk = blockIdx.x, tid = threadIdx.x;

  // ================= phase 0: setup =================
  if (blk < 16) {
    // softmax of b[g][c][:] over 256 labels -> transposed tables.
    // 512 threads: lab = tid&255, half = tid>>8 handles c = half*4+cc.
    int g = blk, lab = tid & 255, half = tid >> 8;
    #pragma unroll
    for (int cc = 0; cc < 4; ++cc) {
      int c = half*4 + cc, row = g*8 + c;
      float x = p.b[row*256 + lab];
      float m = x;
      #pragma unroll
      for (int o2 = 32; o2; o2 >>= 1) m = fmaxf(m, __shfl_xor(m, o2));
      if ((tid & 63) == 0) red[half][(tid >> 6) & 3] = m;
      __syncthreads();
      m = fmaxf(fmaxf(red[half][0], red[half][1]), fmaxf(red[half][2], red[half][3]));
      __syncthreads();
      float e = expf(x - m);
      float s = e;
      #pragma unroll
      for (int o2 = 32; o2; o2 >>= 1) s += __shfl_xor(s, o2);
      if ((tid & 63) == 0) red[half][(tid >> 6) & 3] = s;
      __syncthreads();
      s = red[half][0] + red[half][1] + red[half][2] + red[half][3];
      __syncthreads();
      p.sm_bT[lab*GC + row]  = e / s;
      p.log_bT[lab*GC + row] = (x - m) - logf(s);
    }
  } else if (blk == 16) {
    // a: softmax over i (axis=1) per (g,j,l); a_sp = sm_a * sm_sp; log_a.
    int col = tid;                      // 512 = 16*8*4 exactly
    int g = col >> 5, j = (col >> 2) & 7, l = col & 3;
    float x[8], m = -1e30f;
    #pragma unroll
    for (int i = 0; i < 8; ++i) { x[i] = p.a[g*256 + i*32 + j*4 + l]; m = fmaxf(m, x[i]); }
    float ssum = 0.f;
    #pragma unroll
    for (int i = 0; i < 8; ++i) ssum += expf(x[i] - m);
    float ls = logf(ssum);
    float y0 = p.sp[g*4+0], y1 = p.sp[g*4+1], y2 = p.sp[g*4+2], y3 = p.sp[g*4+3];
    float ms = fmaxf(fmaxf(y0, y1), fmaxf(y2, y3));
    float d = expf(y0-ms) + expf(y1-ms) + expf(y2-ms) + expf(y3-ms);
    float spv = expf(p.sp[g*4+l] - ms) / d;
    #pragma unroll
    for (int i = 0; i < 8; ++i) {
      int o2 = g*256 + i*32 + j*4 + l;
      p.a_sp[o2]  = expf(x[i] - m) / ssum * spv;
      p.log_a[o2] = (x[i] - m) - ls;
    }
  } else if (blk == 17) {
    if (tid < 64) {
      int g = tid >> 2, l = tid & 3;
      float x[8], m = -1e30f;
      #pragma unroll
      for (int c = 0; c < 8; ++c) { x[c] = p.pi[g*32 + c*4 + l]; m = fmaxf(m, x[c]); }
      float ssum = 0.f;
      #pragma unroll
      for (int c = 0; c < 8; ++c) ssum += expf(x[c] - m);
      float ls = logf(ssum);
      #pragma unroll
      for (int c = 0; c < 8; ++c) {
        p.sm_piT[l*GC + g*8 + c]  = expf(x[c] - m) / ssum;
        p.log_piT[l*GC + g*8 + c] = (x[c] - m) - ls;
      }
    } else if (tid < 80) {
      int g = tid - 64;
      float y[4], m = -1e30f;
      #pragma unroll
      for (int l = 0; l < 4; ++l) { y[l] = p.sp[g*4 + l]; m = fmaxf(m, y[l]); }
      float ssum = 0.f;
      #pragma unroll
      for (int l = 0; l < 4; ++l) ssum += expf(y[l] - m);
      float ls = logf(ssum);
      #pragma unroll
      for (int l = 0; l < 4; ++l) p.log_sp[g*4 + l] = (y[l] - m) - ls;
    } else if (tid >= 128 && tid < 144) {
      p.out[tid - 128] = 0.0f;
    }
  }
  grid.sync();   // setup visible device-wide

  // ================= phase 1: up over subtree (LDS) =================
  const int gi = tid & 127, g = gi >> 3, i = gi & 7, g8 = g*8;
  float asp[32];
  {
    const float4* pa = (const float4*)(p.a_sp + g*256 + i*32);
    #pragma unroll
    for (int q = 0; q < 8; ++q) {
      float4 v = pa[q];
      asp[q*4+0]=v.x; asp[q*4+1]=v.y; asp[q*4+2]=v.z; asp[q*4+3]=v.w;
    }
  }
  const int base_leaf = SL + blk*64;
  for (int it = 0; it < 16; ++it) {            // leaves: locals 21..84
    int k = it*4 + (tid >> 7);
    float bt = p.sm_piT[(k & 3)*GC + gi] * p.sm_bT[p.t[(base_leaf + k)*7]*GC + gi];
    float s = grp8_sum(bt);
    sBeta[(21 + k)*GC + gi] = bt / s;
  }
  __syncthreads();
  for (int it = 0; it < 4; ++it) {             // level 6: locals 5..20
    int k = it*4 + (tid >> 7);
    up_lds(5 + k, p.t[(1365 + blk*16 + k)*7], gi, g8, asp, p.sm_bT, sBeta, sNum);
  }
  __syncthreads();
  {                                            // level 5: locals 1..4
    int k = tid >> 7;
    up_lds(1 + k, p.t[(341 + blk*4 + k)*7], gi, g8, asp, p.sm_bT, sBeta, sNum);
  }
  __syncthreads();
  if (tid < 128) {                             // subtree root: local 0
    up_lds(0, p.t[(85 + blk)*7], gi, g8, asp, p.sm_bT, sBeta, sNum);
    p.betaG[(size_t)(85 + blk)*GC + gi] = sBeta[gi];
  }
  grid.sync();   // subtree-root betas visible

  // ================= phase 2: top (blocks 0..15, g-split, global) ========
  if (blk < 16) {
    int it_ = tid & 7, q = tid >> 3, gt = blk*8 + it_, g8t = blk*8;
    float aspt[32], aalt[32], lspt[4];
    {
      const float4* pa = (const float4*)(p.a_sp  + blk*256 + it_*32);
      const float4* pl = (const float4*)(p.log_a + blk*256 + it_*32);
      #pragma unroll
      for (int k = 0; k < 8; ++k) {
        float4 va = pa[k], vl = pl[k];
        aspt[k*4+0]=va.x; aspt[k*4+1]=va.y; aspt[k*4+2]=va.z; aspt[k*4+3]=va.w;
        aalt[k*4+0]=va.x*vl.x; aalt[k*4+1]=va.y*vl.y; aalt[k*4+2]=va.z*vl.z; aalt[k*4+3]=va.w*vl.w;
      }
      #pragma unroll
      for (int l = 0; l < 4; ++l) lspt[l] = p.log_sp[blk*4 + l];
    }
    up_g(21 + q, p.t[(21 + q)*7], gt, g8t, aspt, p.sm_bT, p.betaG, p.numG);
    __syncthreads();
    if (tid < 128) up_g(5 + q, p.t[(5 + q)*7], gt, g8t, aspt, p.sm_bT, p.betaG, p.numG);
    __syncthreads();
    if (tid < 32)  up_g(1 + q, p.t[(1 + q)*7], gt, g8t, aspt, p.sm_bT, p.betaG, p.numG);
    __syncthreads();
    if (tid < 8) {
      up_g(0, p.t[0], gt, g8t, aspt, p.sm_bT, p.betaG, p.numG);
      p.epsG[gt] = p.betaG[gt];
    }
    __syncthreads();
    double acc = 0.0;
    if (tid < 8)
      acc += down_g(0, p.t[0], gt, g8t, aspt, aalt, lspt, p.log_bT, p.numG, p.betaG, p.epsG);
    __syncthreads();
    if (tid < 32)
      acc += down_g(1 + q, p.t[(1 + q)*7], gt, g8t, aspt, aalt, lspt, p.log_bT, p.numG, p.betaG, p.epsG);
    __syncthreads();
    if (tid < 128)
      acc += down_g(5 + q, p.t[(5 + q)*7], gt, g8t, aspt, aalt, lspt, p.log_bT, p.numG, p.betaG, p.epsG);
    __syncthreads();
    acc += down_g(21 + q, p.t[(21 + q)*7], gt, g8t, aspt, aalt, lspt, p.log_bT, p.numG, p.betaG, p.epsG);
    acc += __shfl_xor(acc, 1);
    acc += __shfl_xor(acc, 2);
    acc += __shfl_xor(acc, 4);
    if (it_ == 0) sd[q] = acc;
    __syncthreads();
    if (tid == 0) {
      double s = 0.0;
      for (int k = 0; k < 64; ++k) s += sd[k];
      atomicAdd(&p.out[blk], (float)s);
    }
    __syncthreads();   // protect sd reuse in phase 3
  }
  grid.sync();   // subtree-root eps visible

  // ================= phase 3: down over subtree (LDS) + reduction ========
  float aal[32], lsp[4];
  {
    const float4* pa = (const float4*)(p.a_sp  + g*256 + i*32);
    const float4* pl = (const float4*)(p.log_a + g*256 + i*32);
    #pragma unroll
    for (int k = 0; k < 8; ++k) {
      float4 va = pa[k], vl = pl[k];
      aal[k*4+0]=va.x*vl.x; aal[k*4+1]=va.y*vl.y; aal[k*4+2]=va.z*vl.z; aal[k*4+3]=va.w*vl.w;
    }
    #pragma unroll
    for (int l = 0; l < 4; ++l) lsp[l] = p.log_sp[g*4 + l];
  }
  double acc = 0.0;
  if (tid < 128) {                             // subtree root
    float e = p.epsG[(size_t)(85 + blk)*GC + gi];
    acc += down_lds(0, p.t[(85 + blk)*7], e, gi, g8, asp, aal, lsp, p.log_bT, sBeta, sNum);
  }
  __syncthreads();
  {                                            // level 5
    int k = tid >> 7, v = 1 + k;
    float e = sBeta[v*GC + gi];                // eps written by root step
    acc += down_lds(v, p.t[(341 + blk*4 + k)*7], e, gi, g8, asp, aal, lsp, p.log_bT, sBeta, sNum);
  }
  __syncthreads();
  for (int it = 0; it < 4; ++it) {             // level 6
    int k = it*4 + (tid >> 7), v = 5 + k;
    float e = sBeta[v*GC + gi];
    acc += down_lds(v, p.t[(1365 + blk*16 + k)*7], e, gi, g8, asp, aal, lsp, p.log_bT, sBeta, sNum);
  }
  __syncthreads();
  for (int it = 0; it < 16; ++it) {            // leaves: b_lh + pi_lh
    int k = it*4 + (tid >> 7);
    float e = sBeta[(21 + k)*GC + gi];         // leaf eps
    acc += (double)(e * (p.log_bT[p.t[(base_leaf + k)*7]*GC + gi] +
                         p.log_piT[(k & 3)*GC + gi]));
  }
  acc += __shfl_xor(acc, 1);
  acc += __shfl_xor(acc, 2);
  acc += __shfl_xor(acc, 4);
  if (i == 0) sd[tid >> 3] = acc;              // tid>>3 = chunk*16 + g
  __syncthreads();
  if (tid < 16) {
    double s = sd[tid] + sd[16 + tid] + sd[32 + tid] + sd[48 + tid];
    atomicAdd(&p.out[tid], (float)s);
  }
}

extern "C" void kernel_launch(void* const* d_in, const int* in_sizes, int n_in,
                              void* d_out, int out_size, void* d_ws, size_t ws_size,
                              hipStream_t stream) {
  char* w = (char*)d_ws;
  size_t off = 0;
  auto carve = [&](size_t bytes) -> void* {
    void* ptr = w + off;
    off += (bytes + 255) & ~(size_t)255;
    return ptr;
  };
  P p;
  p.t  = (const int*)d_in[0];
  // d_in[1] = t_limits (tree shape is compile-time constant)
  p.a  = (const float*)d_in[2];
  p.b  = (const float*)d_in[3];
  p.pi = (const float*)d_in[4];
  p.sp = (const float*)d_in[5];
  p.a_sp    = (float*)carve((size_t)16*8*8*4*4);
  p.log_a   = (float*)carve((size_t)16*8*8*4*4);
  p.sm_bT   = (float*)carve((size_t)256*GC*4);
  p.log_bT  = (float*)carve((size_t)256*GC*4);
  p.sm_piT  = (float*)carve((size_t)4*GC*4);
  p.log_piT = (float*)carve((size_t)4*GC*4);
  p.log_sp  = (float*)carve((size_t)16*4*4);
  p.betaG   = (float*)carve((size_t)341*GC*4);
  p.numG    = (float*)carve((size_t)85*GC*4);
  p.epsG    = (float*)carve((size_t)341*GC*4);
  p.out     = (float*)d_out;

  void* args[] = { &p };
  hipLaunchCooperativeKernel((const void*)fused_kernel, dim3(256), dim3(512),
                             args, 0, stream);
}

// Round 5
// 116.568 us; speedup vs baseline: 1.6068x; 1.6068x over previous
//
#include <hip/hip_runtime.h>

// Bottom-up HTMM on a complete 4-ary tree, depth 7 (t_size=21845).
// children(u)=4u+1..4u+4, pos(u)=(u-1)&3; only labels t[u*7] are data.
// prior cancels everywhere (only numbeta = prior*beta_il is used).
// Schedule (4 stream-ordered kernels; NO cooperative grid.sync — measured
// ~25us/sync on 8-XCD MI355X in round 4):
//   setup -> up(256 subtrees, LDS, writes only root betas)
//         -> top(16 g-split blocks, 85 nodes, global L2-hot)
//         -> down(256 subtrees: redo up in LDS, then down in LDS + reduction)
// Subtree local numbering is a complete tree: children(v)=4v+1..4v+4,
// root v=0 <-> global 85+b, leaves v=21..84 <-> 5461+64b+k.

#define G 16
#define C 8
#define GC 128
#define TSIZE 21845
#define SL 5461

__device__ __forceinline__ float grp8_sum(float v) {
  v += __shfl_xor(v, 1);
  v += __shfl_xor(v, 2);
  v += __shfl_xor(v, 4);
  return v;
}

// ---------------- setup: softmaxes + logs (transposed tables) -------------
__global__ void setup_kernel(const float* __restrict__ ain, const float* __restrict__ bin,
                             const float* __restrict__ piin, const float* __restrict__ spin,
                             float* __restrict__ a_sp, float* __restrict__ log_a,
                             float* __restrict__ sm_bT, float* __restrict__ log_bT,
                             float* __restrict__ sm_piT, float* __restrict__ log_piT,
                             float* __restrict__ log_sp, float* __restrict__ out) {
  int blk = blockIdx.x, tid = threadIdx.x;
  if (blk < 16) {
    // softmax over labels (M=256) for b[g][c][:]; write transposed [lab][g*8+c]
    int g = blk;
    __shared__ float red4[4];
    for (int c = 0; c < 8; ++c) {
      int row = g * 8 + c;
      float x = bin[row * 256 + tid];
      float m = x;
      #pragma unroll
      for (int off2 = 32; off2; off2 >>= 1) m = fmaxf(m, __shfl_xor(m, off2));
      if ((tid & 63) == 0) red4[tid >> 6] = m;
      __syncthreads();
      m = fmaxf(fmaxf(red4[0], red4[1]), fmaxf(red4[2], red4[3]));
      __syncthreads();
      float e = expf(x - m);
      float ssum = e;
      #pragma unroll
      for (int off2 = 32; off2; off2 >>= 1) ssum += __shfl_xor(ssum, off2);
      if ((tid & 63) == 0) red4[tid >> 6] = ssum;
      __syncthreads();
      ssum = red4[0] + red4[1] + red4[2] + red4[3];
      __syncthreads();
      sm_bT[tid * GC + row]  = e / ssum;
      log_bT[tid * GC + row] = (x - m) - logf(ssum);
    }
  } else if (blk == 16) {
    // softmax of a over i (axis=1), times sm_sp -> a_sp; also log(sm_a)
    for (int col = tid; col < 512; col += 256) {
      int g = col >> 5, j = (col >> 2) & 7, l = col & 3;
      float x[8], m = -1e30f;
      #pragma unroll
      for (int i = 0; i < 8; ++i) { x[i] = ain[g*256 + i*32 + j*4 + l]; m = fmaxf(m, x[i]); }
      float ssum = 0.f;
      #pragma unroll
      for (int i = 0; i < 8; ++i) ssum += expf(x[i] - m);
      float ls = logf(ssum);
      float y0 = spin[g*4+0], y1 = spin[g*4+1], y2 = spin[g*4+2], y3 = spin[g*4+3];
      float ms = fmaxf(fmaxf(y0, y1), fmaxf(y2, y3));
      float d = expf(y0-ms) + expf(y1-ms) + expf(y2-ms) + expf(y3-ms);
      float spv = expf(spin[g*4+l] - ms) / d;
      #pragma unroll
      for (int i = 0; i < 8; ++i) {
        int o2 = g*256 + i*32 + j*4 + l;
        float smv = expf(x[i] - m) / ssum;
        a_sp[o2]  = smv * spv;
        log_a[o2] = (x[i] - m) - ls;
      }
    }
  } else {
    if (tid < 64) {
      // softmax of pi over c (axis=1) for each (g,l); transposed [l][g*8+c]
      int g = tid >> 2, l = tid & 3;
      float x[8], m = -1e30f;
      #pragma unroll
      for (int c = 0; c < 8; ++c) { x[c] = piin[g*32 + c*4 + l]; m = fmaxf(m, x[c]); }
      float ssum = 0.f;
      #pragma unroll
      for (int c = 0; c < 8; ++c) ssum += expf(x[c] - m);
      float ls = logf(ssum);
      #pragma unroll
      for (int c = 0; c < 8; ++c) {
        sm_piT[l*GC + g*8 + c]  = expf(x[c] - m) / ssum;
        log_piT[l*GC + g*8 + c] = (x[c] - m) - ls;
      }
    } else if (tid < 80) {
      // log softmax of sp over l
      int g = tid - 64;
      float y[4], m = -1e30f;
      #pragma unroll
      for (int l = 0; l < 4; ++l) { y[l] = spin[g*4 + l]; m = fmaxf(m, y[l]); }
      float ssum = 0.f;
      #pragma unroll
      for (int l = 0; l < 4; ++l) ssum += expf(y[l] - m);
      float ls = logf(ssum);
      #pragma unroll
      for (int l = 0; l < 4; ++l) log_sp[g*4 + l] = (y[l] - m) - ls;
    } else if (tid >= 128 && tid < 144) {
      out[tid - 128] = 0.0f;   // zero the accumulator (poisoned 0xAA)
    }
  }
}

// ---------------- LDS subtree bodies (validated in round 4) ---------------
__device__ __forceinline__ void up_lds(int v, int lab, int gi, int g8,
    const float* asp, const float* __restrict__ sm_bT,
    float* sBeta, float* sNum, bool wantNum) {
  int ch0 = 4*v + 1;
  float ub = 0.f;
  #pragma unroll
  for (int l = 0; l < 4; ++l) {
    const float4* bp = (const float4*)(sBeta + (ch0 + l)*GC + g8);
    float4 b0 = bp[0], b1 = bp[1];
    ub += asp[l]*b0.x + asp[4+l]*b0.y + asp[8+l]*b0.z + asp[12+l]*b0.w
        + asp[16+l]*b1.x + asp[20+l]*b1.y + asp[24+l]*b1.z + asp[28+l]*b1.w;
  }
  float tmp = sm_bT[lab*GC + gi] * ub;
  float s = grp8_sum(tmp);
  sBeta[v*GC + gi] = tmp / s;
  if (wantNum) sNum[v*GC + gi] = ub;
}

// eps of node v is passed as e; children's beta slots are overwritten with
// children's eps (safe: per-wave read-before-write, gi-columns disjoint).
__device__ __forceinline__ double down_lds(int v, int lab, float e, int gi, int g8,
    const float* asp, const float* aal, const float* lsp,
    const float* __restrict__ log_bT, float* sBeta, const float* sNum) {
  float pe = e / sNum[v*GC + gi];
  int ch0 = 4*v + 1;
  float local = 0.f;
  #pragma unroll
  for (int l = 0; l < 4; ++l) {
    float4* bp = (float4*)(sBeta + (ch0 + l)*GC + g8);
    float4 b0 = bp[0], b1 = bp[1];
    float S = asp[l]*b0.x + asp[4+l]*b0.y + asp[8+l]*b0.z + asp[12+l]*b0.w
            + asp[16+l]*b1.x + asp[20+l]*b1.y + asp[24+l]*b1.z + asp[28+l]*b1.w;
    float A = aal[l]*b0.x + aal[4+l]*b0.y + aal[8+l]*b0.z + aal[12+l]*b0.w
            + aal[16+l]*b1.x + aal[20+l]*b1.y + aal[24+l]*b1.z + aal[28+l]*b1.w;
    float ce = pe * S;
    sBeta[(ch0 + l)*GC + gi] = ce;          // beta slot -> eps
    local += pe*A + ce*lsp[l];
  }
  return (double)local + (double)(e * log_bT[lab*GC + gi]);
}

// ---------------- global top bodies (nodes 0..340, validated round 3) -----
__device__ __forceinline__ void up_g(int u, int lab, int gi, int g8,
    const float* asp, const float* __restrict__ sm_bT,
    float* __restrict__ betaG, float* __restrict__ numG) {
  int ch0 = 4*u + 1;
  float ub = 0.f;
  #pragma unroll
  for (int l = 0; l < 4; ++l) {
    const float4* bp = (const float4*)(betaG + (size_t)(ch0 + l)*GC + g8);
    float4 b0 = bp[0], b1 = bp[1];
    ub += asp[l]*b0.x + asp[4+l]*b0.y + asp[8+l]*b0.z + asp[12+l]*b0.w
        + asp[16+l]*b1.x + asp[20+l]*b1.y + asp[24+l]*b1.z + asp[28+l]*b1.w;
  }
  float tmp = sm_bT[lab*GC + gi] * ub;
  float s = grp8_sum(tmp);
  betaG[(size_t)u*GC + gi] = tmp / s;
  numG[(size_t)u*GC + gi]  = ub;
}

__device__ __forceinline__ double down_g(int u, int lab, int gi, int g8,
    const float* asp, const float* aal, const float* lsp,
    const float* __restrict__ log_bT, const float* __restrict__ numG,
    const float* __restrict__ betaG, float* __restrict__ epsG) {
  float e  = epsG[(size_t)u*GC + gi];
  float pe = e / numG[(size_t)u*GC + gi];
  int ch0 = 4*u + 1;
  float local = 0.f;
  #pragma unroll
  for (int l = 0; l < 4; ++l) {
    const float4* bp = (const float4*)(betaG + (size_t)(ch0 + l)*GC + g8);
    float4 b0 = bp[0], b1 = bp[1];
    float S = asp[l]*b0.x + asp[4+l]*b0.y + asp[8+l]*b0.z + asp[12+l]*b0.w
            + asp[16+l]*b1.x + asp[20+l]*b1.y + asp[24+l]*b1.z + asp[28+l]*b1.w;
    float A = aal[l]*b0.x + aal[4+l]*b0.y + aal[8+l]*b0.z + aal[12+l]*b0.w
            + aal[16+l]*b1.x + aal[20+l]*b1.y + aal[24+l]*b1.z + aal[28+l]*b1.w;
    float ce = pe * S;
    epsG[(size_t)(ch0 + l)*GC + gi] = ce;
    local += pe*A + ce*lsp[l];
  }
  return (double)local + (double)(e * log_bT[lab*GC + gi]);
}

// ---------------- up: 256 subtrees in LDS, write only root betas ----------
__global__ __launch_bounds__(1024, 1) void up_kernel(
    const float* __restrict__ a_sp, const float* __restrict__ sm_bT,
    const float* __restrict__ sm_piT, const int* __restrict__ t,
    float* __restrict__ betaG) {
  __shared__ float sBeta[85*GC];            // 43.5 KB
  const int blk = blockIdx.x, tid = threadIdx.x;
  const int gi = tid & 127, g = gi >> 3, i = gi & 7, g8 = g*8, w = tid >> 7;
  float asp[32];
  {
    const float4* pa = (const float4*)(a_sp + g*256 + i*32);
    #pragma unroll
    for (int q = 0; q < 8; ++q) {
      float4 v = pa[q];
      asp[q*4+0]=v.x; asp[q*4+1]=v.y; asp[q*4+2]=v.z; asp[q*4+3]=v.w;
    }
  }
  const int base_leaf = SL + blk*64;
  #pragma unroll
  for (int it = 0; it < 8; ++it) {          // leaves: locals 21..84
    int k = it*8 + w;
    float bt = sm_piT[(k & 3)*GC + gi] * sm_bT[t[(base_leaf + k)*7]*GC + gi];
    float s = grp8_sum(bt);
    sBeta[(21 + k)*GC + gi] = bt / s;
  }
  __syncthreads();
  #pragma unroll
  for (int it = 0; it < 2; ++it) {          // level 6: locals 5..20
    int k = it*8 + w;
    up_lds(5 + k, t[(1365 + blk*16 + k)*7], gi, g8, asp, sm_bT, sBeta, nullptr, false);
  }
  __syncthreads();
  if (tid < 512)                            // level 5: locals 1..4
    up_lds(1 + w, t[(341 + blk*4 + w)*7], gi, g8, asp, sm_bT, sBeta, nullptr, false);
  __syncthreads();
  if (tid < 128) {                          // subtree root: local 0
    up_lds(0, t[(85 + blk)*7], gi, g8, asp, sm_bT, sBeta, nullptr, false);
    betaG[(size_t)(85 + blk)*GC + gi] = sBeta[gi];
  }
}

// ---------------- top: g-split, levels 3..0 up then 0..3 down -------------
__global__ __launch_bounds__(512, 2) void top_kernel(
    const float* __restrict__ a_sp, const float* __restrict__ log_a,
    const float* __restrict__ log_sp, const float* __restrict__ sm_bT,
    const float* __restrict__ log_bT, const int* __restrict__ t,
    float* __restrict__ betaG, float* __restrict__ numG,
    float* __restrict__ epsG, float* __restrict__ out) {
  int g = blockIdx.x, tid = threadIdx.x;
  int i = tid & 7, gi = g*8 + i, q = tid >> 3, g8 = g*8;
  float asp[32], aal[32], lsp[4];
  {
    const float4* pa = (const float4*)(a_sp + g*256 + i*32);
    const float4* pl = (const float4*)(log_a + g*256 + i*32);
    #pragma unroll
    for (int k = 0; k < 8; ++k) {
      float4 va = pa[k], vl = pl[k];
      asp[k*4+0]=va.x; asp[k*4+1]=va.y; asp[k*4+2]=va.z; asp[k*4+3]=va.w;
      aal[k*4+0]=va.x*vl.x; aal[k*4+1]=va.y*vl.y; aal[k*4+2]=va.z*vl.z; aal[k*4+3]=va.w*vl.w;
    }
    #pragma unroll
    for (int l = 0; l < 4; ++l) lsp[l] = log_sp[g*4 + l];
  }
  up_g(21 + q, t[(21 + q)*7], gi, g8, asp, sm_bT, betaG, numG);
  __syncthreads();
  if (tid < 128) up_g(5 + q, t[(5 + q)*7], gi, g8, asp, sm_bT, betaG, numG);
  __syncthreads();
  if (tid < 32)  up_g(1 + q, t[(1 + q)*7], gi, g8, asp, sm_bT, betaG, numG);
  __syncthreads();
  if (tid < 8) {
    up_g(0, t[0], gi, g8, asp, sm_bT, betaG, numG);
    epsG[gi] = betaG[gi];
  }
  __syncthreads();
  double acc = 0.0;
  if (tid < 8)
    acc += down_g(0, t[0], gi, g8, asp, aal, lsp, log_bT, numG, betaG, epsG);
  __syncthreads();
  if (tid < 32)
    acc += down_g(1 + q, t[(1 + q)*7], gi, g8, asp, aal, lsp, log_bT, numG, betaG, epsG);
  __syncthreads();
  if (tid < 128)
    acc += down_g(5 + q, t[(5 + q)*7], gi, g8, asp, aal, lsp, log_bT, numG, betaG, epsG);
  __syncthreads();
  acc += down_g(21 + q, t[(21 + q)*7], gi, g8, asp, aal, lsp, log_bT, numG, betaG, epsG);
  acc += __shfl_xor(acc, 1);
  acc += __shfl_xor(acc, 2);
  acc += __shfl_xor(acc, 4);
  __shared__ double sd[64];
  if (i == 0) sd[q] = acc;
  __syncthreads();
  if (tid == 0) {
    double s = 0.0;
    for (int k = 0; k < 64; ++k) s += sd[k];
    atomicAdd(&out[g], (float)s);
  }
}

// ---------------- down: redo subtree up in LDS, then down + reduction -----
__global__ __launch_bounds__(1024, 1) void down_kernel(
    const float* __restrict__ a_sp, const float* __restrict__ log_a,
    const float* __restrict__ log_sp, const float* __restrict__ sm_bT,
    const float* __restrict__ log_bT, const float* __restrict__ sm_piT,
    const float* __restrict__ log_piT, const int* __restrict__ t,
    const float* __restrict__ epsG, float* __restrict__ out) {
  __shared__ float  sBeta[85*GC];           // 43.5 KB; down overwrites w/ eps
  __shared__ float  sNum[21*GC];            // 10.75 KB
  __shared__ double sd[128];
  const int blk = blockIdx.x, tid = threadIdx.x;
  const int gi = tid & 127, g = gi >> 3, i = gi & 7, g8 = g*8, w = tid >> 7;
  float asp[32], aal[32], lsp[4];
  {
    const float4* pa = (const float4*)(a_sp  + g*256 + i*32);
    const float4* pl = (const float4*)(log_a + g*256 + i*32);
    #pragma unroll
    for (int k = 0; k < 8; ++k) {
      float4 va = pa[k], vl = pl[k];
      asp[k*4+0]=va.x; asp[k*4+1]=va.y; asp[k*4+2]=va.z; asp[k*4+3]=va.w;
      aal[k*4+0]=va.x*vl.x; aal[k*4+1]=va.y*vl.y; aal[k*4+2]=va.z*vl.z; aal[k*4+3]=va.w*vl.w;
    }
    #pragma unroll
    for (int l = 0; l < 4; ++l) lsp[l] = log_sp[g*4 + l];
  }
  const int base_leaf = SL + blk*64;
  // ---- redo up (cheap: ~3K FLOP/thread, avoids 14MB global round-trip) ----
  #pragma unroll
  for (int it = 0; it < 8; ++it) {
    int k = it*8 + w;
    float bt = sm_piT[(k & 3)*GC + gi] * sm_bT[t[(base_leaf + k)*7]*GC + gi];
    float s = grp8_sum(bt);
    sBeta[(21 + k)*GC + gi] = bt / s;
  }
  __syncthreads();
  #pragma unroll
  for (int it = 0; it < 2; ++it) {
    int k = it*8 + w;
    up_lds(5 + k, t[(1365 + blk*16 + k)*7], gi, g8, asp, sm_bT, sBeta, sNum, true);
  }
  __syncthreads();
  if (tid < 512)
    up_lds(1 + w, t[(341 + blk*4 + w)*7], gi, g8, asp, sm_bT, sBeta, sNum, true);
  __syncthreads();
  double acc = 0.0;
  if (tid < 128) {
    // root numbeta only (beta[0] not needed; eps comes from epsG)
    up_lds(0, t[(85 + blk)*7], gi, g8, asp, sm_bT, sBeta, sNum, true);
    // ---- down at root (same waves; gi-columns disjoint across waves) ----
    float e = epsG[(size_t)(85 + blk)*GC + gi];
    acc += down_lds(0, t[(85 + blk)*7], e, gi, g8, asp, aal, lsp, log_bT, sBeta, sNum);
  }
  __syncthreads();
  if (tid < 512) {                          // down level 5 (locals 1..4)
    int v = 1 + w;
    float e = sBeta[v*GC + gi];
    acc += down_lds(v, t[(341 + blk*4 + w)*7], e, gi, g8, asp, aal, lsp, log_bT, sBeta, sNum);
  }
  __syncthreads();
  #pragma unroll
  for (int it = 0; it < 2; ++it) {          // down level 6 (locals 5..20)
    int k = it*8 + w, v = 5 + k;
    float e = sBeta[v*GC + gi];
    acc += down_lds(v, t[(1365 + blk*16 + k)*7], e, gi, g8, asp, aal, lsp, log_bT, sBeta, sNum);
  }
  __syncthreads();
  #pragma unroll
  for (int it = 0; it < 8; ++it) {          // leaves: b_lh + pi_lh
    int k = it*8 + w;
    float e = sBeta[(21 + k)*GC + gi];
    acc += (double)(e * (log_bT[t[(base_leaf + k)*7]*GC + gi] +
                         log_piT[(k & 3)*GC + gi]));
  }
  acc += __shfl_xor(acc, 1);
  acc += __shfl_xor(acc, 2);
  acc += __shfl_xor(acc, 4);
  if (i == 0) sd[tid >> 3] = acc;           // tid>>3 = chunk*16 + g
  __syncthreads();
  if (tid < 16) {
    double s = 0.0;
    #pragma unroll
    for (int c = 0; c < 8; ++c) s += sd[tid + 16*c];
    atomicAdd(&out[tid], (float)s);
  }
}

extern "C" void kernel_launch(void* const* d_in, const int* in_sizes, int n_in,
                              void* d_out, int out_size, void* d_ws, size_t ws_size,
                              hipStream_t stream) {
  const int*   t  = (const int*)d_in[0];
  // d_in[1] = t_limits (tree shape is compile-time constant)
  const float* a  = (const float*)d_in[2];
  const float* b  = (const float*)d_in[3];
  const float* pi = (const float*)d_in[4];
  const float* sp = (const float*)d_in[5];
  float* out = (float*)d_out;

  char* w = (char*)d_ws;
  size_t off = 0;
  auto carve = [&](size_t bytes) -> void* {
    void* ptr = w + off;
    off += (bytes + 255) & ~(size_t)255;
    return ptr;
  };
  float* a_sp    = (float*)carve((size_t)16*8*8*4*4);
  float* log_a   = (float*)carve((size_t)16*8*8*4*4);
  float* sm_bT   = (float*)carve((size_t)256*GC*4);
  float* log_bT  = (float*)carve((size_t)256*GC*4);
  float* sm_piT  = (float*)carve((size_t)4*GC*4);
  float* log_piT = (float*)carve((size_t)4*GC*4);
  float* log_sp  = (float*)carve((size_t)16*4*4);
  float* betaG   = (float*)carve((size_t)341*GC*4);   // top + subtree roots
  float* numG    = (float*)carve((size_t)85*GC*4);    // top internal
  float* epsG    = (float*)carve((size_t)341*GC*4);   // top + subtree roots

  setup_kernel<<<18, 256, 0, stream>>>(a, b, pi, sp, a_sp, log_a, sm_bT, log_bT,
                                       sm_piT, log_piT, log_sp, out);
  up_kernel<<<256, 1024, 0, stream>>>(a_sp, sm_bT, sm_piT, t, betaG);
  top_kernel<<<16, 512, 0, stream>>>(a_sp, log_a, log_sp, sm_bT, log_bT, t,
                                     betaG, numG, epsG, out);
  down_kernel<<<256, 1024, 0, stream>>>(a_sp, log_a, log_sp, sm_bT, log_bT,
                                        sm_piT, log_piT, t, epsG, out);
}